// Round 6
// baseline (456.355 us; speedup 1.0000x reference)
//
#include <hip/hip_runtime.h>

#define Bn 4
#define Sn 2048
#define Dn 1024
#define Hn 16
#define DHn 64

typedef float f32x4 __attribute__((ext_vector_type(4)));
typedef short bf16x8 __attribute__((ext_vector_type(8)));
typedef unsigned short u16;
typedef unsigned int u32;
typedef unsigned short u16x8 __attribute__((ext_vector_type(8)));
typedef unsigned short u16x4 __attribute__((ext_vector_type(4)));
typedef u32 u32x4 __attribute__((ext_vector_type(4)));

union B8 { u32x4 u; bf16x8 s; u16x8 h; };

__device__ __forceinline__ u16 f2bf(float f){
  union { float f; u32 u; } v; v.f = f;
  return (u16)((v.u + 0x7fffu + ((v.u >> 16) & 1u)) >> 16);
}

// truncating pack: two fp32 -> {bf16(lo) | bf16(hi)<<16}. P>0 -> -0.2% uniform bias, negligible.
__device__ __forceinline__ u32 pack_bf2(float lo, float hi){
  union { float f; u32 u; } a, b;
  a.f = lo; b.f = hi;
  return __builtin_amdgcn_perm(b.u, a.u, 0x07060302u);
}

#if __has_builtin(__builtin_amdgcn_exp2f)
#define EXP2(x) __builtin_amdgcn_exp2f(x)
#define QSCALE 0.18033688011112042f   /* 0.125 * log2(e) */
#else
#define EXP2(x) __expf(x)
#define QSCALE 0.125f
#endif

#if __has_builtin(__builtin_amdgcn_global_load_lds)
#define G2L16(l, g) __builtin_amdgcn_global_load_lds((const __attribute__((address_space(1))) u32*)(g), \
                                                     (__attribute__((address_space(3))) u32*)(l), 16, 0, 0)
#else
#define G2L16(l, g) (*(bf16x8*)(l) = *(const bf16x8*)(g))
#endif

// ---------------- merged prep: cast x (blocks 0..4095) + 4 weights (4096..5119) ----------------
__global__ void prep_kernel(const float* __restrict__ x,
                            const float* __restrict__ Wq, const float* __restrict__ Wk,
                            const float* __restrict__ Wv, const float* __restrict__ Wo,
                            u16* __restrict__ xb, u16* __restrict__ wt_all){
  __shared__ u16 tile[64*66];
  const int t = threadIdx.x;
  if (blockIdx.x < 4096){
    size_t i = ((size_t)blockIdx.x * 256 + t) * 8;
    float4 f0 = *(const float4*)(x + i);
    float4 f1 = *(const float4*)(x + i + 4);
    u16x8 o;
    o[0]=f2bf(f0.x); o[1]=f2bf(f0.y); o[2]=f2bf(f0.z); o[3]=f2bf(f0.w);
    o[4]=f2bf(f1.x); o[5]=f2bf(f1.y); o[6]=f2bf(f1.z); o[7]=f2bf(f1.w);
    *(u16x8*)(xb + i) = o;
    return;
  }
  const int wi = blockIdx.x - 4096;
  const int z = wi >> 8, r8 = wi & 255;
  const int k0 = (r8 >> 4) * 64, n0 = (r8 & 15) * 64;
  const float* w = (z == 0) ? Wq : (z == 1) ? Wk : (z == 2) ? Wv : Wo;
  const float scale = (z == 0) ? QSCALE : 1.0f;
  u16* wt = wt_all + (size_t)z * Dn * Dn;
  #pragma unroll
  for (int i = 0; i < 4; i++){
    int idx = i*256 + t;
    int r = idx >> 4, c4 = (idx & 15) * 4;
    float4 f = *(const float4*)(w + (size_t)(k0 + r)*Dn + n0 + c4);
    tile[r*66 + c4 + 0] = f2bf(f.x * scale);
    tile[r*66 + c4 + 1] = f2bf(f.y * scale);
    tile[r*66 + c4 + 2] = f2bf(f.z * scale);
    tile[r*66 + c4 + 3] = f2bf(f.w * scale);
  }
  __syncthreads();
  #pragma unroll
  for (int i = 0; i < 4; i++){
    int idx = i*256 + t;
    int nr = idx >> 4, kc4 = (idx & 15) * 4;
    u16x4 o;
    o[0] = tile[(kc4+0)*66 + nr];
    o[1] = tile[(kc4+1)*66 + nr];
    o[2] = tile[(kc4+2)*66 + nr];
    o[3] = tile[(kc4+3)*66 + nr];
    *(u16x4*)(wt + (size_t)(n0 + nr)*Dn + k0 + kc4) = o;
  }
}

// ---------------- QKV GEMM: C[8192x1024] = xb * Wt^T ----------------
// smem union: AB double-buffer (32KB) unioned with epilogue Cs (34.8KB).
// launch_bounds(256,3): cap total regs at 170 (108 VGPR + 64 AGPR = 172 was 2
// regs over the 3-waves/SIMD cliff at 170; this is the occupancy knob, not LDS).
__launch_bounds__(256, 3)
__global__ void gemm_qkv_kernel(const u16* __restrict__ xb, const u16* __restrict__ wt_all,
                                u16* __restrict__ qb, u16* __restrict__ kb, u16* __restrict__ vtb){
  __shared__ u16 smem[128*136];   // 34816 B
  const int t = threadIdx.x;
  const int wave = t >> 6, lane = t & 63;
  const int ln = lane & 15, quad = lane >> 4;
  const int wm = wave >> 1, wn = wave & 1;
  const int n0 = blockIdx.x * 128;
  const int m0 = blockIdx.y * 128;
  const int zsel = blockIdx.z;
  const u16* wt = wt_all + (size_t)zsel * Dn * Dn;

  f32x4 acc[4][4] = {};

  #pragma unroll
  for (int i = 0; i < 2; i++){
    int idx = i*256 + t;
    int r = idx >> 2, c8 = (idx & 3) * 8;
    G2L16(&smem[idx*8],        xb + (size_t)(m0 + r)*Dn + c8);
    G2L16(&smem[4096 + idx*8], wt + (size_t)(n0 + r)*Dn + c8);
  }

  for (int ki = 0; ki < 32; ki++){
    const int cur = ki & 1;
    __syncthreads();
    if (ki + 1 < 32){
      const int nxt = 8192 * ((ki+1) & 1);
      const int kt = (ki+1) * 32;
      #pragma unroll
      for (int i = 0; i < 2; i++){
        int idx = i*256 + t;
        int r = idx >> 2, c8 = (idx & 3) * 8;
        G2L16(&smem[nxt + idx*8],        xb + (size_t)(m0 + r)*Dn + kt + c8);
        G2L16(&smem[nxt + 4096 + idx*8], wt + (size_t)(n0 + r)*Dn + kt + c8);
      }
    }
    const u16* As = &smem[8192*cur];
    const u16* Bs = &smem[8192*cur + 4096];
    bf16x8 a[4], b[4];
    #pragma unroll
    for (int rb = 0; rb < 4; rb++) a[rb] = *(const bf16x8*)&As[(wm*64 + rb*16 + ln)*32 + quad*8];
    #pragma unroll
    for (int cb = 0; cb < 4; cb++) b[cb] = *(const bf16x8*)&Bs[(wn*64 + cb*16 + ln)*32 + quad*8];
    #pragma unroll
    for (int rb = 0; rb < 4; rb++)
      #pragma unroll
      for (int cb = 0; cb < 4; cb++)
        acc[rb][cb] = __builtin_amdgcn_mfma_f32_16x16x32_bf16(a[rb], b[cb], acc[rb][cb], 0, 0, 0);
  }

  __syncthreads();
  u16* Cs = smem;
  if (zsel < 2){
    #pragma unroll
    for (int rb = 0; rb < 4; rb++)
      #pragma unroll
      for (int cb = 0; cb < 4; cb++)
        #pragma unroll
        for (int reg = 0; reg < 4; reg++)
          Cs[(wm*64 + rb*16 + quad*4 + reg)*136 + wn*64 + cb*16 + ln] = f2bf(acc[rb][cb][reg]);
  } else {
    #pragma unroll
    for (int rb = 0; rb < 4; rb++)
      #pragma unroll
      for (int cb = 0; cb < 4; cb++){
        u16x4 o;
        #pragma unroll
        for (int reg = 0; reg < 4; reg++) o[reg] = f2bf(acc[rb][cb][reg]);
        *(u16x4*)&Cs[(wn*64 + cb*16 + ln)*136 + wm*64 + rb*16 + quad*4] = o;
      }
  }
  __syncthreads();

  if (zsel < 2){
    u16* outp = (zsel == 0) ? qb : kb;
    #pragma unroll
    for (int i = 0; i < 8; i++){
      int idx = i*256 + t;
      int r = idx >> 4, c8 = (idx & 15) * 8;
      bf16x8 vdat = *(const bf16x8*)&Cs[r*136 + c8];
      int row = m0 + r, bb = row >> 11, s = row & 2047;
      int col = n0 + c8, hh = col >> 6, d = col & 63;
      *(bf16x8*)(outp + (((size_t)bb*Hn + hh)*Sn + s)*DHn + d) = vdat;
    }
  } else {
    #pragma unroll
    for (int i = 0; i < 8; i++){
      int idx = i*256 + t;
      int c = idx >> 4, r8 = (idx & 15) * 8;
      bf16x8 vdat = *(const bf16x8*)&Cs[c*136 + r8];
      int col = n0 + c, hh = col >> 6, d = col & 63;
      int row = m0 + r8, bb = row >> 11, s = row & 2047;
      *(bf16x8*)(vtb + (((size_t)bb*Hn + hh)*DHn + d)*Sn + s) = vdat;
    }
  }
}

// ---------------- attention: S^T formulation, 64 q/wave, pipelined, ks-split ----------------
// launch_bounds(256,3): 112 VGPR + 64 AGPR = 176 was over the 170-reg
// 3-waves/SIMD cliff; force allocator to shave ~6 regs for +50% occupancy.
__launch_bounds__(256, 3)
__global__ void attn_kernel(const u16* q, const u16* __restrict__ k,
                            const u16* __restrict__ vt, u16* z){
  __shared__ u16 Ks[2][64*72];   // [key][d]
  __shared__ u16 Vs[2][64*72];   // [d][key'] column-shuffled: col'=ks*32+quad*8+j
  const int t = threadIdx.x;
  const int wave = t >> 6, lane = t & 63;
  const int ln = lane & 15, quad = lane >> 4;
  const int qt = blockIdx.x, h = blockIdx.y, b = blockIdx.z;
  const size_t bh = (size_t)b * Hn + h;
  const int q0 = qt*256 + wave*64;
  const u16* qp = q + bh * Sn * DHn;
  const u16* kp = k + bh * Sn * DHn;
  const u16* vp = vt + bh * DHn * Sn;

  bf16x8 qf[4][2];
  #pragma unroll
  for (int n = 0; n < 4; n++)
    #pragma unroll
    for (int kq = 0; kq < 2; kq++)
      qf[n][kq] = *(const bf16x8*)(qp + (size_t)(q0 + n*16 + ln)*DHn + kq*32 + quad*8);

  f32x4 zacc[4][4] = {};
  float dacc[4] = {0.f, 0.f, 0.f, 0.f};

  int sr[2], sc[2], vc1[2], vc2[2];
  #pragma unroll
  for (int i = 0; i < 2; i++){
    int idx = i*256 + t, r = idx >> 3, a = idx & 7;
    sr[i] = r; sc[i] = a*8;
    int ksg = a >> 2, q1 = ((a&3)*2)&3, h1 = (a&3) >> 1;
    vc1[i] = ksg*32 + q1*8 + h1*4;
    vc2[i] = ksg*32 + (((q1+1)&3))*8 + h1*4;
  }

  bf16x8 rk[2], rv[2];
  #pragma unroll
  for (int i = 0; i < 2; i++){
    rk[i] = *(const bf16x8*)(kp + (size_t)sr[i]*DHn + sc[i]);
    rv[i] = *(const bf16x8*)(vp + (size_t)sr[i]*Sn + sc[i]);
  }
  #pragma unroll
  for (int i = 0; i < 2; i++){
    *(bf16x8*)&Ks[0][sr[i]*72 + sc[i]] = rk[i];
    u16x4 lo = *(u16x4*)&rv[i];
    u16x4 hi = *((u16x4*)&rv[i] + 1);
    *(u16x4*)&Vs[0][sr[i]*72 + vc1[i]] = lo;
    *(u16x4*)&Vs[0][sr[i]*72 + vc2[i]] = hi;
  }

  for (int kt = 0; kt < Sn/64; kt++){
    const int cur = kt & 1;
    __syncthreads();

    if (kt + 1 < Sn/64){
      #pragma unroll
      for (int i = 0; i < 2; i++){
        rk[i] = *(const bf16x8*)(kp + (size_t)((kt+1)*64 + sr[i])*DHn + sc[i]);
        rv[i] = *(const bf16x8*)(vp + (size_t)sr[i]*Sn + (kt+1)*64 + sc[i]);
      }
    }
    const u16* Kc = Ks[cur];
    const u16* Vc = Vs[cur];

    #pragma unroll
    for (int ks = 0; ks < 2; ks++){
      f32x4 sacc[2][4] = {};
      #pragma unroll
      for (int kq = 0; kq < 2; kq++){
        bf16x8 ka[2];
        #pragma unroll
        for (int m2 = 0; m2 < 2; m2++)
          ka[m2] = *(const bf16x8*)&Kc[((2*ks + m2)*16 + ln)*72 + kq*32 + quad*8];
        #pragma unroll
        for (int m2 = 0; m2 < 2; m2++)
          #pragma unroll
          for (int n = 0; n < 4; n++)
            sacc[m2][n] = __builtin_amdgcn_mfma_f32_16x16x32_bf16(ka[m2], qf[n][kq], sacc[m2][n], 0, 0, 0);
      }
      B8 pb[4];
      #pragma unroll
      for (int n = 0; n < 4; n++){
        f32x4 s0 = sacc[0][n], s1 = sacc[1][n];
        float a0 = EXP2(s0[0]), a1 = EXP2(s0[1]), a2 = EXP2(s0[2]), a3 = EXP2(s0[3]);
        float b0 = EXP2(s1[0]), b1 = EXP2(s1[1]), b2 = EXP2(s1[2]), b3 = EXP2(s1[3]);
        dacc[n] += ((a0 + a1) + (a2 + a3)) + ((b0 + b1) + (b2 + b3));
        pb[n].u = (u32x4){pack_bf2(a0, a1), pack_bf2(a2, a3), pack_bf2(b0, b1), pack_bf2(b2, b3)};
      }
      #pragma unroll
      for (int mtd = 0; mtd < 4; mtd++){
        bf16x8 va = *(const bf16x8*)&Vc[(mtd*16 + ln)*72 + ks*32 + quad*8];
        #pragma unroll
        for (int n = 0; n < 4; n++)
          zacc[mtd][n] = __builtin_amdgcn_mfma_f32_16x16x32_bf16(va, pb[n].s, zacc[mtd][n], 0, 0, 0);
      }
    }

    if (kt + 1 < Sn/64){
      const int nxt = (kt+1) & 1;
      #pragma unroll
      for (int i = 0; i < 2; i++){
        *(bf16x8*)&Ks[nxt][sr[i]*72 + sc[i]] = rk[i];
        u16x4 lo = *(u16x4*)&rv[i];
        u16x4 hi = *((u16x4*)&rv[i] + 1);
        *(u16x4*)&Vs[nxt][sr[i]*72 + vc1[i]] = lo;
        *(u16x4*)&Vs[nxt][sr[i]*72 + vc2[i]] = hi;
      }
    }
  }

  float inv[4];
  #pragma unroll
  for (int n = 0; n < 4; n++){
    float d = dacc[n];
    d += __shfl_xor(d, 16, 64);
    d += __shfl_xor(d, 32, 64);
    inv[n] = 1.0f / d;
  }

  #pragma unroll
  for (int mtd = 0; mtd < 4; mtd++)
    #pragma unroll
    for (int n = 0; n < 4; n++){
      u16x4 o;
      #pragma unroll
      for (int j = 0; j < 4; j++) o[j] = f2bf(zacc[mtd][n][j] * inv[n]);
      *(u16x4*)(z + (bh*Sn + (size_t)(q0 + n*16 + ln))*DHn + mtd*16 + quad*4) = o;
    }
}

// ---------------- out = z * Wout^T + x  (fp32 out), dbuf single-barrier ----------------
__launch_bounds__(256, 3)
__global__ void gemm_out_kernel(const u16* __restrict__ zb, const u16* __restrict__ wt,
                                const float* __restrict__ x, float* __restrict__ out){
  __shared__ u16 smem[2][2][128*32];
  const int t = threadIdx.x;
  const int wave = t >> 6, lane = t & 63;
  const int ln = lane & 15, quad = lane >> 4;
  const int wm = wave >> 1, wn = wave & 1;
  const int n0 = blockIdx.x * 128;
  const int m0 = blockIdx.y * 128;

  f32x4 acc[4][4] = {};

  #pragma unroll
  for (int i = 0; i < 2; i++){
    int idx = i*256 + t;
    int r = idx >> 2, c8 = (idx & 3) * 8;
    int row = m0 + r, bb = row >> 11, s = row & 2047;
    G2L16(&smem[0][0][idx*8], zb + (((size_t)bb*Hn + 0)*Sn + s)*DHn + 0 + c8);
    G2L16(&smem[0][1][idx*8], wt + (size_t)(n0 + r)*Dn + c8);
  }

  for (int ki = 0; ki < 32; ki++){
    const int cur = ki & 1;
    __syncthreads();
    if (ki + 1 < 32){
      const int nxt = (ki+1) & 1;
      const int kt = (ki+1) * 32;
      const int hh = kt >> 6, d0 = kt & 63;
      #pragma unroll
      for (int i = 0; i < 2; i++){
        int idx = i*256 + t;
        int r = idx >> 2, c8 = (idx & 3) * 8;
        int row = m0 + r, bb = row >> 11, s = row & 2047;
        G2L16(&smem[nxt][0][idx*8], zb + (((size_t)bb*Hn + hh)*Sn + s)*DHn + d0 + c8);
        G2L16(&smem[nxt][1][idx*8], wt + (size_t)(n0 + r)*Dn + kt + c8);
      }
    }
    const u16* As = smem[cur][0];
    const u16* Bs = smem[cur][1];
    bf16x8 a[4], b[4];
    #pragma unroll
    for (int rb = 0; rb < 4; rb++) a[rb] = *(const bf16x8*)&As[(wm*64 + rb*16 + ln)*32 + quad*8];
    #pragma unroll
    for (int cb = 0; cb < 4; cb++) b[cb] = *(const bf16x8*)&Bs[(wn*64 + cb*16 + ln)*32 + quad*8];
    #pragma unroll
    for (int rb = 0; rb < 4; rb++)
      #pragma unroll
      for (int cb = 0; cb < 4; cb++)
        acc[rb][cb] = __builtin_amdgcn_mfma_f32_16x16x32_bf16(a[rb], b[cb], acc[rb][cb], 0, 0, 0);
  }

  #pragma unroll
  for (int rb = 0; rb < 4; rb++)
    #pragma unroll
    for (int cb = 0; cb < 4; cb++)
      #pragma unroll
      for (int reg = 0; reg < 4; reg++){
        int row = m0 + wm*64 + rb*16 + quad*4 + reg;
        int col = n0 + wn*64 + cb*16 + ln;
        size_t off = (size_t)row*Dn + col;
        out[off] = acc[rb][cb][reg] + x[off];
      }
}

extern "C" void kernel_launch(void* const* d_in, const int* in_sizes, int n_in,
                              void* d_out, int out_size, void* d_ws, size_t ws_size,
                              hipStream_t stream){
  const float* x    = (const float*)d_in[0];
  const float* Wq   = (const float*)d_in[2];
  const float* Wk   = (const float*)d_in[3];
  const float* Wv   = (const float*)d_in[4];
  const float* Wout = (const float*)d_in[5];
  float* out = (float*)d_out;

  u16* ws = (u16*)d_ws;
  const size_t NW = (size_t)Dn * Dn;
  const size_t NX = (size_t)Bn * Sn * Dn;
  u16* wt  = ws;                // Wq^T(scaled),Wk^T,Wv^T,Wout^T
  u16* xb  = wt + 4*NW;         // x bf16
  u16* qb  = xb + NX;           // Q [b,h,s,d] (attn writes z in-place)
  u16* kb  = qb + NX;           // K [b,h,s,d]
  u16* vtb = kb + NX;           // Vt [b,h,d,s] (written directly by gemm_qkv)

  dim3 blk(256);
  prep_kernel     <<<dim3(4096 + 1024), blk, 0, stream>>>(x, Wq, Wk, Wv, Wout, xb, wt);
  gemm_qkv_kernel <<<dim3(8,64,3), blk, 0, stream>>>(xb, wt, qb, kb, vtb);
  attn_kernel     <<<dim3(8,16,4), blk, 0, stream>>>(qb, kb, vtb, qb);
  gemm_out_kernel <<<dim3(8,64), blk, 0, stream>>>(qb, wt + 3*NW, x, out);
}

// Round 7
// 276.652 us; speedup vs baseline: 1.6496x; 1.6496x over previous
//
#include <hip/hip_runtime.h>

#define Bn 4
#define Sn 2048
#define Dn 1024
#define Hn 16
#define DHn 64

typedef float f32x4 __attribute__((ext_vector_type(4)));
typedef short bf16x8 __attribute__((ext_vector_type(8)));
typedef unsigned short u16;
typedef unsigned int u32;
typedef unsigned short u16x8 __attribute__((ext_vector_type(8)));
typedef unsigned short u16x4 __attribute__((ext_vector_type(4)));
typedef u32 u32x4 __attribute__((ext_vector_type(4)));

union B8 { u32x4 u; bf16x8 s; u16x8 h; };

__device__ __forceinline__ u16 f2bf(float f){
  union { float f; u32 u; } v; v.f = f;
  return (u16)((v.u + 0x7fffu + ((v.u >> 16) & 1u)) >> 16);
}

// truncating pack: two fp32 -> {bf16(lo) | bf16(hi)<<16}. P>0 -> -0.2% uniform bias, negligible.
__device__ __forceinline__ u32 pack_bf2(float lo, float hi){
  union { float f; u32 u; } a, b;
  a.f = lo; b.f = hi;
  return __builtin_amdgcn_perm(b.u, a.u, 0x07060302u);
}

#if __has_builtin(__builtin_amdgcn_exp2f)
#define EXP2(x) __builtin_amdgcn_exp2f(x)
#define QSCALE 0.18033688011112042f   /* 0.125 * log2(e) */
#else
#define EXP2(x) __expf(x)
#define QSCALE 0.125f
#endif

#if __has_builtin(__builtin_amdgcn_global_load_lds)
#define G2L16(l, g) __builtin_amdgcn_global_load_lds((const __attribute__((address_space(1))) u32*)(g), \
                                                     (__attribute__((address_space(3))) u32*)(l), 16, 0, 0)
#else
#define G2L16(l, g) (*(bf16x8*)(l) = *(const bf16x8*)(g))
#endif

// ---------------- merged prep: cast x (blocks 0..4095) + 4 weights (4096..5119) ----------------
__global__ void prep_kernel(const float* __restrict__ x,
                            const float* __restrict__ Wq, const float* __restrict__ Wk,
                            const float* __restrict__ Wv, const float* __restrict__ Wo,
                            u16* __restrict__ xb, u16* __restrict__ wt_all){
  __shared__ u16 tile[64*66];
  const int t = threadIdx.x;
  if (blockIdx.x < 4096){
    size_t i = ((size_t)blockIdx.x * 256 + t) * 8;
    float4 f0 = *(const float4*)(x + i);
    float4 f1 = *(const float4*)(x + i + 4);
    u16x8 o;
    o[0]=f2bf(f0.x); o[1]=f2bf(f0.y); o[2]=f2bf(f0.z); o[3]=f2bf(f0.w);
    o[4]=f2bf(f1.x); o[5]=f2bf(f1.y); o[6]=f2bf(f1.z); o[7]=f2bf(f1.w);
    *(u16x8*)(xb + i) = o;
    return;
  }
  const int wi = blockIdx.x - 4096;
  const int z = wi >> 8, r8 = wi & 255;
  const int k0 = (r8 >> 4) * 64, n0 = (r8 & 15) * 64;
  const float* w = (z == 0) ? Wq : (z == 1) ? Wk : (z == 2) ? Wv : Wo;
  const float scale = (z == 0) ? QSCALE : 1.0f;
  u16* wt = wt_all + (size_t)z * Dn * Dn;
  #pragma unroll
  for (int i = 0; i < 4; i++){
    int idx = i*256 + t;
    int r = idx >> 4, c4 = (idx & 15) * 4;
    float4 f = *(const float4*)(w + (size_t)(k0 + r)*Dn + n0 + c4);
    tile[r*66 + c4 + 0] = f2bf(f.x * scale);
    tile[r*66 + c4 + 1] = f2bf(f.y * scale);
    tile[r*66 + c4 + 2] = f2bf(f.z * scale);
    tile[r*66 + c4 + 3] = f2bf(f.w * scale);
  }
  __syncthreads();
  #pragma unroll
  for (int i = 0; i < 4; i++){
    int idx = i*256 + t;
    int nr = idx >> 4, kc4 = (idx & 15) * 4;
    u16x4 o;
    o[0] = tile[(kc4+0)*66 + nr];
    o[1] = tile[(kc4+1)*66 + nr];
    o[2] = tile[(kc4+2)*66 + nr];
    o[3] = tile[(kc4+3)*66 + nr];
    *(u16x4*)(wt + (size_t)(n0 + nr)*Dn + k0 + kc4) = o;
  }
}

// ---------------- QKV GEMM: C[8192x1024] = xb * Wt^T ----------------
// BK=64: two proven pitch-32 sub-stages under ONE barrier per 64-K (halves
// barrier/vmcnt-drain count; LDS bytes/FLOP unchanged). LDS = 2 stages x 32KB
// = 64KB, Cs (34.8KB) unioned. 2 blocks/CU (reg-capped at ~172 unified regs;
// NO launch_bounds min-waves — forcing 3 waves/SIMD spills acc, +630MB scratch).
__launch_bounds__(256)
__global__ void gemm_qkv_kernel(const u16* __restrict__ xb, const u16* __restrict__ wt_all,
                                u16* __restrict__ qb, u16* __restrict__ kb, u16* __restrict__ vtb){
  __shared__ u16 smem[32768];   // 64 KB
  const int t = threadIdx.x;
  const int wave = t >> 6, lane = t & 63;
  const int ln = lane & 15, quad = lane >> 4;
  const int wm = wave >> 1, wn = wave & 1;
  const int n0 = blockIdx.x * 128;
  const int m0 = blockIdx.y * 128;
  const int zsel = blockIdx.z;
  const u16* wt = wt_all + (size_t)zsel * Dn * Dn;

  f32x4 acc[4][4] = {};

  // staging coords: idx=i*256+t, r=idx>>2, c8=(idx&3)*8; stage layout:
  // smem[stage*16384 + sub*8192 + (A:0|B:4096) + idx*8]
  #pragma unroll
  for (int sub = 0; sub < 2; sub++)
    #pragma unroll
    for (int i = 0; i < 2; i++){
      int idx = i*256 + t;
      int r = idx >> 2, c8 = (idx & 3) * 8;
      G2L16(&smem[sub*8192 + idx*8],        xb + (size_t)(m0 + r)*Dn + sub*32 + c8);
      G2L16(&smem[sub*8192 + 4096 + idx*8], wt + (size_t)(n0 + r)*Dn + sub*32 + c8);
    }

  for (int ki = 0; ki < 16; ki++){
    const int cur = ki & 1;
    __syncthreads();
    if (ki + 1 < 16){
      const int nxt = 16384 * ((ki+1) & 1);
      const int kt = (ki+1) * 64;
      #pragma unroll
      for (int sub = 0; sub < 2; sub++)
        #pragma unroll
        for (int i = 0; i < 2; i++){
          int idx = i*256 + t;
          int r = idx >> 2, c8 = (idx & 3) * 8;
          G2L16(&smem[nxt + sub*8192 + idx*8],        xb + (size_t)(m0 + r)*Dn + kt + sub*32 + c8);
          G2L16(&smem[nxt + sub*8192 + 4096 + idx*8], wt + (size_t)(n0 + r)*Dn + kt + sub*32 + c8);
        }
    }
    #pragma unroll
    for (int sub = 0; sub < 2; sub++){
      const u16* As = &smem[16384*cur + sub*8192];
      const u16* Bs = As + 4096;
      bf16x8 a[4], b[4];
      #pragma unroll
      for (int rb = 0; rb < 4; rb++) a[rb] = *(const bf16x8*)&As[(wm*64 + rb*16 + ln)*32 + quad*8];
      #pragma unroll
      for (int cb = 0; cb < 4; cb++) b[cb] = *(const bf16x8*)&Bs[(wn*64 + cb*16 + ln)*32 + quad*8];
      #pragma unroll
      for (int rb = 0; rb < 4; rb++)
        #pragma unroll
        for (int cb = 0; cb < 4; cb++)
          acc[rb][cb] = __builtin_amdgcn_mfma_f32_16x16x32_bf16(a[rb], b[cb], acc[rb][cb], 0, 0, 0);
    }
  }

  __syncthreads();
  u16* Cs = smem;
  if (zsel < 2){
    #pragma unroll
    for (int rb = 0; rb < 4; rb++)
      #pragma unroll
      for (int cb = 0; cb < 4; cb++)
        #pragma unroll
        for (int reg = 0; reg < 4; reg++)
          Cs[(wm*64 + rb*16 + quad*4 + reg)*136 + wn*64 + cb*16 + ln] = f2bf(acc[rb][cb][reg]);
  } else {
    #pragma unroll
    for (int rb = 0; rb < 4; rb++)
      #pragma unroll
      for (int cb = 0; cb < 4; cb++){
        u16x4 o;
        #pragma unroll
        for (int reg = 0; reg < 4; reg++) o[reg] = f2bf(acc[rb][cb][reg]);
        *(u16x4*)&Cs[(wn*64 + cb*16 + ln)*136 + wm*64 + rb*16 + quad*4] = o;
      }
  }
  __syncthreads();

  if (zsel < 2){
    u16* outp = (zsel == 0) ? qb : kb;
    #pragma unroll
    for (int i = 0; i < 8; i++){
      int idx = i*256 + t;
      int r = idx >> 4, c8 = (idx & 15) * 8;
      bf16x8 vdat = *(const bf16x8*)&Cs[r*136 + c8];
      int row = m0 + r, bb = row >> 11, s = row & 2047;
      int col = n0 + c8, hh = col >> 6, d = col & 63;
      *(bf16x8*)(outp + (((size_t)bb*Hn + hh)*Sn + s)*DHn + d) = vdat;
    }
  } else {
    #pragma unroll
    for (int i = 0; i < 8; i++){
      int idx = i*256 + t;
      int c = idx >> 4, r8 = (idx & 15) * 8;
      bf16x8 vdat = *(const bf16x8*)&Cs[c*136 + r8];
      int col = n0 + c, hh = col >> 6, d = col & 63;
      int row = m0 + r8, bb = row >> 11, s = row & 2047;
      *(bf16x8*)(vtb + (((size_t)bb*Hn + hh)*DHn + d)*Sn + s) = vdat;
    }
  }
}

// ---------------- attention: S^T formulation, 64 q/wave, pipelined, ks-split ----------------
// Exactly the R4 version: (256,2). (256,3) spilled acc -> 632MB scratch writes.
__launch_bounds__(256, 2)
__global__ void attn_kernel(const u16* q, const u16* __restrict__ k,
                            const u16* __restrict__ vt, u16* z){
  __shared__ u16 Ks[2][64*72];   // [key][d]
  __shared__ u16 Vs[2][64*72];   // [d][key'] column-shuffled: col'=ks*32+quad*8+j
  const int t = threadIdx.x;
  const int wave = t >> 6, lane = t & 63;
  const int ln = lane & 15, quad = lane >> 4;
  const int qt = blockIdx.x, h = blockIdx.y, b = blockIdx.z;
  const size_t bh = (size_t)b * Hn + h;
  const int q0 = qt*256 + wave*64;
  const u16* qp = q + bh * Sn * DHn;
  const u16* kp = k + bh * Sn * DHn;
  const u16* vp = vt + bh * DHn * Sn;

  bf16x8 qf[4][2];
  #pragma unroll
  for (int n = 0; n < 4; n++)
    #pragma unroll
    for (int kq = 0; kq < 2; kq++)
      qf[n][kq] = *(const bf16x8*)(qp + (size_t)(q0 + n*16 + ln)*DHn + kq*32 + quad*8);

  f32x4 zacc[4][4] = {};
  float dacc[4] = {0.f, 0.f, 0.f, 0.f};

  int sr[2], sc[2], vc1[2], vc2[2];
  #pragma unroll
  for (int i = 0; i < 2; i++){
    int idx = i*256 + t, r = idx >> 3, a = idx & 7;
    sr[i] = r; sc[i] = a*8;
    int ksg = a >> 2, q1 = ((a&3)*2)&3, h1 = (a&3) >> 1;
    vc1[i] = ksg*32 + q1*8 + h1*4;
    vc2[i] = ksg*32 + (((q1+1)&3))*8 + h1*4;
  }

  bf16x8 rk[2], rv[2];
  #pragma unroll
  for (int i = 0; i < 2; i++){
    rk[i] = *(const bf16x8*)(kp + (size_t)sr[i]*DHn + sc[i]);
    rv[i] = *(const bf16x8*)(vp + (size_t)sr[i]*Sn + sc[i]);
  }
  #pragma unroll
  for (int i = 0; i < 2; i++){
    *(bf16x8*)&Ks[0][sr[i]*72 + sc[i]] = rk[i];
    u16x4 lo = *(u16x4*)&rv[i];
    u16x4 hi = *((u16x4*)&rv[i] + 1);
    *(u16x4*)&Vs[0][sr[i]*72 + vc1[i]] = lo;
    *(u16x4*)&Vs[0][sr[i]*72 + vc2[i]] = hi;
  }

  for (int kt = 0; kt < Sn/64; kt++){
    const int cur = kt & 1;
    __syncthreads();

    if (kt + 1 < Sn/64){
      #pragma unroll
      for (int i = 0; i < 2; i++){
        rk[i] = *(const bf16x8*)(kp + (size_t)((kt+1)*64 + sr[i])*DHn + sc[i]);
        rv[i] = *(const bf16x8*)(vp + (size_t)sr[i]*Sn + (kt+1)*64 + sc[i]);
      }
    }
    const u16* Kc = Ks[cur];
    const u16* Vc = Vs[cur];

    #pragma unroll
    for (int ks = 0; ks < 2; ks++){
      f32x4 sacc[2][4] = {};
      #pragma unroll
      for (int kq = 0; kq < 2; kq++){
        bf16x8 ka[2];
        #pragma unroll
        for (int m2 = 0; m2 < 2; m2++)
          ka[m2] = *(const bf16x8*)&Kc[((2*ks + m2)*16 + ln)*72 + kq*32 + quad*8];
        #pragma unroll
        for (int m2 = 0; m2 < 2; m2++)
          #pragma unroll
          for (int n = 0; n < 4; n++)
            sacc[m2][n] = __builtin_amdgcn_mfma_f32_16x16x32_bf16(ka[m2], qf[n][kq], sacc[m2][n], 0, 0, 0);
      }
      B8 pb[4];
      #pragma unroll
      for (int n = 0; n < 4; n++){
        f32x4 s0 = sacc[0][n], s1 = sacc[1][n];
        float a0 = EXP2(s0[0]), a1 = EXP2(s0[1]), a2 = EXP2(s0[2]), a3 = EXP2(s0[3]);
        float b0 = EXP2(s1[0]), b1 = EXP2(s1[1]), b2 = EXP2(s1[2]), b3 = EXP2(s1[3]);
        dacc[n] += ((a0 + a1) + (a2 + a3)) + ((b0 + b1) + (b2 + b3));
        pb[n].u = (u32x4){pack_bf2(a0, a1), pack_bf2(a2, a3), pack_bf2(b0, b1), pack_bf2(b2, b3)};
      }
      #pragma unroll
      for (int mtd = 0; mtd < 4; mtd++){
        bf16x8 va = *(const bf16x8*)&Vc[(mtd*16 + ln)*72 + ks*32 + quad*8];
        #pragma unroll
        for (int n = 0; n < 4; n++)
          zacc[mtd][n] = __builtin_amdgcn_mfma_f32_16x16x32_bf16(va, pb[n].s, zacc[mtd][n], 0, 0, 0);
      }
    }

    if (kt + 1 < Sn/64){
      const int nxt = (kt+1) & 1;
      #pragma unroll
      for (int i = 0; i < 2; i++){
        *(bf16x8*)&Ks[nxt][sr[i]*72 + sc[i]] = rk[i];
        u16x4 lo = *(u16x4*)&rv[i];
        u16x4 hi = *((u16x4*)&rv[i] + 1);
        *(u16x4*)&Vs[nxt][sr[i]*72 + vc1[i]] = lo;
        *(u16x4*)&Vs[nxt][sr[i]*72 + vc2[i]] = hi;
      }
    }
  }

  float inv[4];
  #pragma unroll
  for (int n = 0; n < 4; n++){
    float d = dacc[n];
    d += __shfl_xor(d, 16, 64);
    d += __shfl_xor(d, 32, 64);
    inv[n] = 1.0f / d;
  }

  #pragma unroll
  for (int mtd = 0; mtd < 4; mtd++)
    #pragma unroll
    for (int n = 0; n < 4; n++){
      u16x4 o;
      #pragma unroll
      for (int j = 0; j < 4; j++) o[j] = f2bf(zacc[mtd][n][j] * inv[n]);
      *(u16x4*)(z + (bh*Sn + (size_t)(q0 + n*16 + ln))*DHn + mtd*16 + quad*4) = o;
    }
}

// ---------------- out = z * Wout^T + x  (fp32 out), BK=64 single-barrier dbuf ----------------
// K-chunk of 64 == exactly one head of z: ki = head, sub*32 = d-offset.
__launch_bounds__(256)
__global__ void gemm_out_kernel(const u16* __restrict__ zb, const u16* __restrict__ wt,
                                const float* __restrict__ x, float* __restrict__ out){
  __shared__ u16 smem[32768];   // 64 KB: 2 stages x (A0 B0 A1 B1)
  const int t = threadIdx.x;
  const int wave = t >> 6, lane = t & 63;
  const int ln = lane & 15, quad = lane >> 4;
  const int wm = wave >> 1, wn = wave & 1;
  const int n0 = blockIdx.x * 128;
  const int m0 = blockIdx.y * 128;

  f32x4 acc[4][4] = {};

  #pragma unroll
  for (int sub = 0; sub < 2; sub++)
    #pragma unroll
    for (int i = 0; i < 2; i++){
      int idx = i*256 + t;
      int r = idx >> 2, c8 = (idx & 3) * 8;
      int row = m0 + r, bb = row >> 11, s = row & 2047;
      G2L16(&smem[sub*8192 + idx*8],        zb + (((size_t)bb*Hn + 0)*Sn + s)*DHn + sub*32 + c8);
      G2L16(&smem[sub*8192 + 4096 + idx*8], wt + (size_t)(n0 + r)*Dn + sub*32 + c8);
    }

  for (int ki = 0; ki < 16; ki++){
    const int cur = ki & 1;
    __syncthreads();
    if (ki + 1 < 16){
      const int nxt = 16384 * ((ki+1) & 1);
      const int hh = ki + 1;           // 64-K chunk == head hh, d0 = sub*32
      const int kt = (ki+1) * 64;
      #pragma unroll
      for (int sub = 0; sub < 2; sub++)
        #pragma unroll
        for (int i = 0; i < 2; i++){
          int idx = i*256 + t;
          int r = idx >> 2, c8 = (idx & 3) * 8;
          int row = m0 + r, bb = row >> 11, s = row & 2047;
          G2L16(&smem[nxt + sub*8192 + idx*8],        zb + (((size_t)bb*Hn + hh)*Sn + s)*DHn + sub*32 + c8);
          G2L16(&smem[nxt + sub*8192 + 4096 + idx*8], wt + (size_t)(n0 + r)*Dn + kt + sub*32 + c8);
        }
    }
    #pragma unroll
    for (int sub = 0; sub < 2; sub++){
      const u16* As = &smem[16384*cur + sub*8192];
      const u16* Bs = As + 4096;
      bf16x8 a[4], b[4];
      #pragma unroll
      for (int rb = 0; rb < 4; rb++) a[rb] = *(const bf16x8*)&As[(wm*64 + rb*16 + ln)*32 + quad*8];
      #pragma unroll
      for (int cb = 0; cb < 4; cb++) b[cb] = *(const bf16x8*)&Bs[(wn*64 + cb*16 + ln)*32 + quad*8];
      #pragma unroll
      for (int rb = 0; rb < 4; rb++)
        #pragma unroll
        for (int cb = 0; cb < 4; cb++)
          acc[rb][cb] = __builtin_amdgcn_mfma_f32_16x16x32_bf16(a[rb], b[cb], acc[rb][cb], 0, 0, 0);
    }
  }

  #pragma unroll
  for (int rb = 0; rb < 4; rb++)
    #pragma unroll
    for (int cb = 0; cb < 4; cb++)
      #pragma unroll
      for (int reg = 0; reg < 4; reg++){
        int row = m0 + wm*64 + rb*16 + quad*4 + reg;
        int col = n0 + wn*64 + cb*16 + ln;
        size_t off = (size_t)row*Dn + col;
        out[off] = acc[rb][cb][reg] + x[off];
      }
}

extern "C" void kernel_launch(void* const* d_in, const int* in_sizes, int n_in,
                              void* d_out, int out_size, void* d_ws, size_t ws_size,
                              hipStream_t stream){
  const float* x    = (const float*)d_in[0];
  const float* Wq   = (const float*)d_in[2];
  const float* Wk   = (const float*)d_in[3];
  const float* Wv   = (const float*)d_in[4];
  const float* Wout = (const float*)d_in[5];
  float* out = (float*)d_out;

  u16* ws = (u16*)d_ws;
  const size_t NW = (size_t)Dn * Dn;
  const size_t NX = (size_t)Bn * Sn * Dn;
  u16* wt  = ws;                // Wq^T(scaled),Wk^T,Wv^T,Wout^T
  u16* xb  = wt + 4*NW;         // x bf16
  u16* qb  = xb + NX;           // Q [b,h,s,d] (attn writes z in-place)
  u16* kb  = qb + NX;           // K [b,h,s,d]
  u16* vtb = kb + NX;           // Vt [b,h,d,s] (written directly by gemm_qkv)

  dim3 blk(256);
  prep_kernel     <<<dim3(4096 + 1024), blk, 0, stream>>>(x, Wq, Wk, Wv, Wout, xb, wt);
  gemm_qkv_kernel <<<dim3(8,64,3), blk, 0, stream>>>(xb, wt, qb, kb, vtb);
  attn_kernel     <<<dim3(8,16,4), blk, 0, stream>>>(qb, kb, vtb, qb);
  gemm_out_kernel <<<dim3(8,64), blk, 0, stream>>>(qb, wt + 3*NW, x, out);
}